// Round 9
// baseline (175.085 us; speedup 1.0000x reference)
//
#include <hip/hip_runtime.h>

// ActorCriticLoss fused kernel, v3: minimize ds_bpermute traffic.
//   out[0 .. B*T)        = sigmoid(logits)
//   out[B*T .. B*T+B*63) = lambda returns (reverse affine scan over T)
//
// Geometry: 16 lanes per row, 4 timesteps per lane, 4 rows per wave.
//   lane = g*16 + q ; row = wid*4 + g ; lane owns t = 4q .. 4q+3.
// Recurrence C_t = a_t*C_{t+1} + b_t (C_63 seeded by v63 via identity map):
//   a_t = GAMMA*LAMDA*c_t ; b_t = r_t + GAMMA*(1-LAMDA)*c_t*v_{t+1}
// Per lane: compose 4 maps serially (VALU). Cross-lane: 4-step suffix scan
// over 16 lanes (one bpermute pair serves all 4 rows at once) + 1 shift for
// the exclusive carry. Total 10 bpermutes/wave = 2.5/row (was 13/row --
// LDS-pipe throughput was the round-4/7 bottleneck at ~61us).
// v63 / boundary v_{t+1} come from L1-broadcast global loads (VMEM idle).

constexpr float GAMMA = 0.997f;
constexpr float LAMDA = 0.95f;
constexpr int T = 64;

__global__ __launch_bounds__(256) void fused_k(const float* __restrict__ logits,
                                               const float* __restrict__ rew,
                                               const float* __restrict__ con,
                                               const float* __restrict__ val,
                                               float* __restrict__ out_sig,
                                               float* __restrict__ out_ret,
                                               int B) {
  const int gid  = blockIdx.x * blockDim.x + threadIdx.x;
  const int wid  = gid >> 6;
  const int lane = gid & 63;
  const int g    = lane >> 4;     // group (row within wave)
  const int q    = lane & 15;     // 4-timestep slot within row
  const int row  = wid * 4 + g;
  if (row >= B) return;

  const size_t rbase = (size_t)row * T;
  constexpr float GL  = GAMMA * LAMDA;          // a_t coefficient
  constexpr float G1L = GAMMA * (1.0f - LAMDA); // b_t blend coefficient

  // ---- loads: 4x dwordx4 + 2 broadcast dwords, all issued up front ----
  const float4 x = ((const float4*)(logits + rbase))[q];
  const float4 r = ((const float4*)(rew    + rbase))[q];
  const float4 c = ((const float4*)(con    + rbase))[q];
  const float4 v = ((const float4*)(val    + rbase))[q];
  const float v63 = val[rbase + 63];                          // bootstrap
  const float vnx = val[rbase + ((q < 15) ? 4 * q + 4 : 63)]; // v_{4q+4}

  // ---- sigmoid (aligned float4 store) ----
  float4 s;
  s.x = 1.0f / (1.0f + __expf(-x.x));
  s.y = 1.0f / (1.0f + __expf(-x.y));
  s.z = 1.0f / (1.0f + __expf(-x.z));
  s.w = 1.0f / (1.0f + __expf(-x.w));
  ((float4*)(out_sig + rbase))[q] = s;

  // ---- per-timestep affine maps (t = 4q+j) ----
  const float a0 = GL * c.x, b0 = fmaf(G1L * c.x, v.y, r.x);
  const float a1 = GL * c.y, b1 = fmaf(G1L * c.y, v.z, r.y);
  const float a2 = GL * c.z, b2 = fmaf(G1L * c.z, v.w, r.z);
  float a3, b3;
  if (q == 15) { a3 = 1.0f; b3 = 0.0f; }        // t=63: identity (seed pass)
  else         { a3 = GL * c.w; b3 = fmaf(G1L * c.w, vnx, r.w); }

  // ---- compose lane's block map: C_{4q} = A*C_{4q+4} + B ----
  float A = a3, Bb = b3;
  A = a2 * A; Bb = fmaf(a2, Bb, b2);
  A = a1 * A; Bb = fmaf(a1, Bb, b1);
  A = a0 * A; Bb = fmaf(a0, Bb, b0);

  // ---- 4-step suffix scan over the 16-lane group (8 bpermutes) ----
#pragma unroll
  for (int d = 1; d < 16; d <<= 1) {
    int src = lane + d; if (src > 63) src = 63;
    float Ain = __shfl(A, src);
    float Bin = __shfl(Bb, src);
    const bool ok = (q + d) < 16;        // identity beyond group end
    Ain = ok ? Ain : 1.0f;
    Bin = ok ? Bin : 0.0f;
    Bb = fmaf(A, Bin, Bb);               // self o src (src is later in time)
    A  = A * Ain;
  }

  // ---- exclusive carry C_{4q+4} via +1 shift (2 bpermutes) ----
  int srcx = lane + 1; if (srcx > 63) srcx = 63;
  float Aex = __shfl(A, srcx);
  float Bex = __shfl(Bb, srcx);
  const bool okx = q < 15;
  Aex = okx ? Aex : 1.0f;
  Bex = okx ? Bex : 0.0f;
  const float carry = fmaf(Aex, v63, Bex);   // C_{4q+4}

  // ---- apply within lane and store (63 floats/row; scalar, coalesced) ----
  const float c3 = fmaf(a3, carry, b3);      // C_{4q+3}
  const float c2 = fmaf(a2, c3, b2);
  const float c1 = fmaf(a1, c2, b1);
  const float c0 = fmaf(a0, c1, b0);
  float* orow = out_ret + (size_t)row * 63 + 4 * q;
  orow[0] = c0;
  orow[1] = c1;
  orow[2] = c2;
  if (q < 15) orow[3] = c3;                  // t=63 not an output
}

extern "C" void kernel_launch(void* const* d_in, const int* in_sizes, int n_in,
                              void* d_out, int out_size, void* d_ws, size_t ws_size,
                              hipStream_t stream) {
  const float* logits = (const float*)d_in[0];
  const float* rew    = (const float*)d_in[1];
  const float* con    = (const float*)d_in[2];
  const float* val    = (const float*)d_in[3];
  float* out = (float*)d_out;

  const int BT = in_sizes[0];   // B*T
  const int B  = BT / T;

  float* out_sig = out;                  // B*T floats
  float* out_ret = out + (size_t)BT;     // B*63 floats

  // 4 rows per wave, 4 waves per block -> 16 rows per block
  const int blocks = (B + 15) / 16;
  fused_k<<<blocks, 256, 0, stream>>>(logits, rew, con, val, out_sig, out_ret, B);
}